// Round 9
// baseline (698.302 us; speedup 1.0000x reference)
//
#include <hip/hip_runtime.h>
#include <math.h>

#define NN 100000
#define NE 1600000
#define D 64
#define DE 32
#define NB_SCAN ((NN + 255) / 256)   // 391

typedef __attribute__((ext_vector_type(8))) short short8;
typedef __attribute__((ext_vector_type(4))) float f32x4;

__device__ __forceinline__ int rfl(int v){ return __builtin_amdgcn_readfirstlane(v); }

#define LEAKY(v) ((v) > 0.f ? (v) : 0.2f*(v))

__device__ __forceinline__ unsigned short f2bf(float x){
  unsigned u = __float_as_uint(x);
  unsigned r = (u + 0x7fffu + ((u >> 16) & 1u)) >> 16;
  return (unsigned short)r;
}
__device__ __forceinline__ float bf2f(unsigned short b){
  return __uint_as_float(((unsigned)b) << 16);
}

// cursor doubles as deg accumulator
__global__ __launch_bounds__(256) void k_deg(const int* __restrict__ dst, int* __restrict__ cursor){
  int i = blockIdx.x*256 + threadIdx.x;
  if (i < NE) atomicAdd(&cursor[dst[i]], 1);
}

__global__ __launch_bounds__(256) void k_scan_a(const int* __restrict__ deg, int* __restrict__ bsum){
  __shared__ int sh[256];
  int tid = threadIdx.x;
  int i = blockIdx.x*256 + tid;
  sh[tid] = (i < NN) ? deg[i] : 0;
  __syncthreads();
  for (int s = 128; s > 0; s >>= 1){
    if (tid < s) sh[tid] += sh[tid+s];
    __syncthreads();
  }
  if (tid == 0) bsum[blockIdx.x] = sh[0];
}

__global__ __launch_bounds__(512) void k_scan_b(int* __restrict__ bsum, int* __restrict__ rowptr){
  __shared__ int tmp[512];
  int tid = threadIdx.x;
  int v = (tid < NB_SCAN) ? bsum[tid] : 0;
  tmp[tid] = v;
  __syncthreads();
  for (int off = 1; off < 512; off <<= 1){
    int t = (tid >= off) ? tmp[tid-off] : 0;
    __syncthreads();
    tmp[tid] += t;
    __syncthreads();
  }
  if (tid < NB_SCAN) bsum[tid] = tmp[tid] - v;
  if (tid == 511) rowptr[NN] = tmp[511];
}

// reads cursor (=deg), writes rowptr and resets cursor to the exclusive offset
__global__ __launch_bounds__(256) void k_scan_c(const int* bsum, int* rowptr, int* cursor){
  __shared__ int tmp[256];
  int tid = threadIdx.x;
  int i = blockIdx.x*256 + tid;
  int v = (i < NN) ? cursor[i] : 0;
  tmp[tid] = v;
  __syncthreads();
  for (int off = 1; off < 256; off <<= 1){
    int t = (tid >= off) ? tmp[tid-off] : 0;
    __syncthreads();
    tmp[tid] += t;
    __syncthreads();
  }
  if (i < NN){
    int excl = tmp[tid] - v + bsum[blockIdx.x];
    rowptr[i] = excl;
    cursor[i] = excl;
  }
}

// slot[pos]=edge id of CSR slot, ssrc[pos]=src node of CSR slot
__global__ __launch_bounds__(256) void k_scatter(const int* __restrict__ srcp, const int* __restrict__ dstp,
                                                 int* __restrict__ cursor,
                                                 int* __restrict__ slot, int* __restrict__ ssrc){
  int i = blockIdx.x*256 + threadIdx.x;
  if (i < NE){
    int d = dstp[i];
    int pos = atomicAdd(&cursor[d], 1);
    slot[pos] = i;
    ssrc[pos] = srcp[i];
  }
}

// t_csr[i][j] = bf16( (eattr[slot[i]] @ We)[j] )  via mfma_f32_16x16x32_bf16.
// One wave per 16 CSR slots (R6-proven body). Random 128B-aligned row reads
// (vector loads), sequential writes. Both layers in one eattr pass.
__global__ __launch_bounds__(256) void k_t(const float* __restrict__ eattr,
                                           const int* __restrict__ slot,
                                           const float* __restrict__ We1,
                                           const float* __restrict__ We2,
                                           unsigned short* __restrict__ t1,
                                           unsigned short* __restrict__ t2){
  int lane = threadIdx.x & 63;
  int wid = blockIdx.x*(blockDim.x>>6) + (threadIdx.x>>6);
  int nw = gridDim.x*(blockDim.x>>6);
  int r = lane & 15;    // A: edge row within tile; B/D: output col within 16-tile
  int g = lane >> 4;    // k-group (A/B), row-group (D)
  // B fragments: wb[t][i] = We[(8g+i)][16t + r]
  short8 wb1[4], wb2[4];
  #pragma unroll
  for (int t = 0; t < 4; ++t){
    #pragma unroll
    for (int i = 0; i < 8; ++i){
      wb1[t][i] = (short)f2bf(We1[(8*g + i)*D + 16*t + r]);
      wb2[t][i] = (short)f2bf(We2[(8*g + i)*D + 16*t + r]);
    }
  }
  for (int i0 = wid*16; i0 < NE; i0 += nw*16){
    int sl = slot[i0 + r];
    const float* ea = eattr + (size_t)sl*DE + 8*g;
    float4 q0 = *(const float4*)(ea);
    float4 q1 = *(const float4*)(ea + 4);
    short8 a;
    a[0]=(short)f2bf(q0.x); a[1]=(short)f2bf(q0.y); a[2]=(short)f2bf(q0.z); a[3]=(short)f2bf(q0.w);
    a[4]=(short)f2bf(q1.x); a[5]=(short)f2bf(q1.y); a[6]=(short)f2bf(q1.z); a[7]=(short)f2bf(q1.w);
    f32x4 d0={0.f,0.f,0.f,0.f}, d1={0.f,0.f,0.f,0.f}, d2={0.f,0.f,0.f,0.f}, d3={0.f,0.f,0.f,0.f};
    d0 = __builtin_amdgcn_mfma_f32_16x16x32_bf16(a, wb1[0], d0, 0, 0, 0);
    d1 = __builtin_amdgcn_mfma_f32_16x16x32_bf16(a, wb1[1], d1, 0, 0, 0);
    d2 = __builtin_amdgcn_mfma_f32_16x16x32_bf16(a, wb1[2], d2, 0, 0, 0);
    d3 = __builtin_amdgcn_mfma_f32_16x16x32_bf16(a, wb1[3], d3, 0, 0, 0);
    size_t rb = (size_t)(i0 + 4*g)*D + r;   // row 4g+i, col 16t+r
    #pragma unroll
    for (int i = 0; i < 4; ++i){
      t1[rb + (size_t)i*D +  0] = f2bf(d0[i]);
      t1[rb + (size_t)i*D + 16] = f2bf(d1[i]);
      t1[rb + (size_t)i*D + 32] = f2bf(d2[i]);
      t1[rb + (size_t)i*D + 48] = f2bf(d3[i]);
    }
    f32x4 e0={0.f,0.f,0.f,0.f}, e1={0.f,0.f,0.f,0.f}, e2={0.f,0.f,0.f,0.f}, e3={0.f,0.f,0.f,0.f};
    e0 = __builtin_amdgcn_mfma_f32_16x16x32_bf16(a, wb2[0], e0, 0, 0, 0);
    e1 = __builtin_amdgcn_mfma_f32_16x16x32_bf16(a, wb2[1], e1, 0, 0, 0);
    e2 = __builtin_amdgcn_mfma_f32_16x16x32_bf16(a, wb2[2], e2, 0, 0, 0);
    e3 = __builtin_amdgcn_mfma_f32_16x16x32_bf16(a, wb2[3], e3, 0, 0, 0);
    #pragma unroll
    for (int i = 0; i < 4; ++i){
      t2[rb + (size_t)i*D +  0] = f2bf(e0[i]);
      t2[rb + (size_t)i*D + 16] = f2bf(e1[i]);
      t2[rb + (size_t)i*D + 32] = f2bf(e2[i]);
      t2[rb + (size_t)i*D + 48] = f2bf(e3[i]);
    }
  }
}

// xl[n][j] = bf16( b[j] + sum_k x[n][k]*W[k][j] )   (bf16 rows: 128B = 1 line)
__global__ __launch_bounds__(256) void k_lin(const float* __restrict__ xin, const float* __restrict__ W,
                                             const float* __restrict__ b, unsigned short* __restrict__ xl){
  int lane = threadIdx.x & 63;
  int wid = blockIdx.x*(blockDim.x>>6) + (threadIdx.x>>6);
  int nw = gridDim.x*(blockDim.x>>6);
  float wcol[D];
  #pragma unroll
  for (int kk = 0; kk < D; ++kk) wcol[kk] = W[kk*D + lane];
  float bj = b[lane];
  for (int n0 = wid; n0 < NN; n0 += nw){
    int n = rfl(n0);
    const float* xr = xin + (size_t)n*D;
    float acc = bj;
    #pragma unroll
    for (int kk = 0; kk < D; ++kk) acc = fmaf(xr[kk], wcol[kk], acc);
    xl[(size_t)n*D + lane] = f2bf(acc);
  }
}

#define RED64(c) { _Pragma("unroll") for (int off = 32; off > 0; off >>= 1) c += __shfl_xor(c, off, 64); }

// Fused per-destination: logit + softmax + aggregate. Software-pipelined
// batches of 4; xl gathered as bf16 (128B rows).
__global__ __launch_bounds__(256) void k_node(const int* __restrict__ rowptr,
                                              const int* __restrict__ ssrc,
                                              const unsigned short* __restrict__ t_csr,
                                              const float* __restrict__ att,
                                              const unsigned short* __restrict__ xl,
                                              const float* __restrict__ bias,
                                              float* __restrict__ outp){
  int lane = threadIdx.x & 63;
  int wid = blockIdx.x*(blockDim.x>>6) + (threadIdx.x>>6);
  int nw = gridDim.x*(blockDim.x>>6);
  float attj = att[lane];
  float bj = bias[lane];
  for (int n0 = wid; n0 < NN; n0 += nw){
    int n = rfl(n0);
    int st = rowptr[n], en = rowptr[n+1];
    float xd = bf2f(xl[(size_t)n*D + lane]);
    float tsum = 0.f;
    float den0 = 0.f, den1 = 0.f, acc0 = 0.f, acc1 = 0.f;
    int i = st;
    // ---- pipelined batches of 4 ----
    float ttA0=0, ttA1=0, ttA2=0, ttA3=0;
    float xsA0=0, xsA1=0, xsA2=0, xsA3=0;
    bool haveA = (i + 4 <= en);
    if (haveA){
      int s0 = ssrc[i], s1 = ssrc[i+1], s2 = ssrc[i+2], s3 = ssrc[i+3];
      ttA0 = bf2f(t_csr[(size_t)(i  )*D + lane]);
      ttA1 = bf2f(t_csr[(size_t)(i+1)*D + lane]);
      ttA2 = bf2f(t_csr[(size_t)(i+2)*D + lane]);
      ttA3 = bf2f(t_csr[(size_t)(i+3)*D + lane]);
      xsA0 = bf2f(xl[(size_t)s0*D + lane]);
      xsA1 = bf2f(xl[(size_t)s1*D + lane]);
      xsA2 = bf2f(xl[(size_t)s2*D + lane]);
      xsA3 = bf2f(xl[(size_t)s3*D + lane]);
    }
    while (haveA){
      int ni = i + 4;
      bool haveB = (ni + 4 <= en);
      float ttB0=0, ttB1=0, ttB2=0, ttB3=0;
      float xsB0=0, xsB1=0, xsB2=0, xsB3=0;
      if (haveB){
        int s0 = ssrc[ni], s1 = ssrc[ni+1], s2 = ssrc[ni+2], s3 = ssrc[ni+3];
        ttB0 = bf2f(t_csr[(size_t)(ni  )*D + lane]);
        ttB1 = bf2f(t_csr[(size_t)(ni+1)*D + lane]);
        ttB2 = bf2f(t_csr[(size_t)(ni+2)*D + lane]);
        ttB3 = bf2f(t_csr[(size_t)(ni+3)*D + lane]);
        xsB0 = bf2f(xl[(size_t)s0*D + lane]);
        xsB1 = bf2f(xl[(size_t)s1*D + lane]);
        xsB2 = bf2f(xl[(size_t)s2*D + lane]);
        xsB3 = bf2f(xl[(size_t)s3*D + lane]);
      }
      // compute current batch A (loads for B are in flight)
      tsum += (ttA0 + ttA1) + (ttA2 + ttA3);
      float c0 = LEAKY(xsA0 + xd + ttA0) * attj;
      float c1 = LEAKY(xsA1 + xd + ttA1) * attj;
      float c2 = LEAKY(xsA2 + xd + ttA2) * attj;
      float c3 = LEAKY(xsA3 + xd + ttA3) * attj;
      #pragma unroll
      for (int off = 32; off > 0; off >>= 1){
        c0 += __shfl_xor(c0, off, 64);
        c1 += __shfl_xor(c1, off, 64);
        c2 += __shfl_xor(c2, off, 64);
        c3 += __shfl_xor(c3, off, 64);
      }
      float p0 = __expf(c0), p1 = __expf(c1), p2 = __expf(c2), p3 = __expf(c3);
      den0 += p0 + p1;
      den1 += p2 + p3;
      acc0 = fmaf(p0, xsA0, acc0);
      acc0 = fmaf(p1, xsA1, acc0);
      acc1 = fmaf(p2, xsA2, acc1);
      acc1 = fmaf(p3, xsA3, acc1);
      ttA0=ttB0; ttA1=ttB1; ttA2=ttB2; ttA3=ttB3;
      xsA0=xsB0; xsA1=xsB1; xsA2=xsB2; xsA3=xsB3;
      i = ni;
      haveA = haveB;
    }
    // ---- tail ----
    for (; i < en; ++i){
      int s = ssrc[i];
      float t = bf2f(t_csr[(size_t)i*D + lane]);
      float xs = bf2f(xl[(size_t)s*D + lane]);
      tsum += t;
      float c = LEAKY(xs + xd + t) * attj;
      RED64(c)
      float p = __expf(c);
      den0 += p;
      acc0 = fmaf(p, xs, acc0);
    }
    // self loop: t_self = mean(t_e) by linearity; 0 for isolated nodes
    float degf = (float)(en - st);
    float ts = tsum / fmaxf(degf, 1.f);
    float cs = LEAKY(xd + xd + ts) * attj;
    RED64(cs)
    float ps = __expf(cs);
    float den = den0 + den1 + ps;
    float acc = fmaf(ps, xd, acc0 + acc1);
    outp[(size_t)n*D + lane] = acc/den + bj;
  }
}

extern "C" void kernel_launch(void* const* d_in, const int* in_sizes, int n_in,
                              void* d_out, int out_size, void* d_ws, size_t ws_size,
                              hipStream_t stream){
  const float* x     = (const float*)d_in[0];
  const int*   ei    = (const int*)d_in[1];
  const float* eattr = (const float*)d_in[2];
  const float* W1    = (const float*)d_in[3];
  const float* b1    = (const float*)d_in[4];
  const float* We1   = (const float*)d_in[5];
  const float* att1  = (const float*)d_in[6];
  const float* bias1 = (const float*)d_in[7];
  const float* W2    = (const float*)d_in[8];
  const float* b2    = (const float*)d_in[9];
  const float* We2   = (const float*)d_in[10];
  const float* att2  = (const float*)d_in[11];
  const float* bias2 = (const float*)d_in[12];
  const int* srcp = ei;
  const int* dstp = ei + NE;
  float* out = (float*)d_out;

  char* p = (char*)d_ws;
  size_t off = 0;
  auto alloc = [&](size_t bytes)->char*{
    char* r = p + off; off = (off + bytes + 255) & ~(size_t)255; return r;
  };
  int* rowptr   = (int*)alloc((size_t)(NN+1)*4);
  int* cursor   = (int*)alloc((size_t)NN*4);       // also deg accumulator
  int* bsum     = (int*)alloc(512*4);
  int* slot     = (int*)alloc((size_t)NE*4);
  int* ssrc     = (int*)alloc((size_t)NE*4);
  unsigned short* xl = (unsigned short*)alloc((size_t)NN*D*2);  // bf16 rows
  float* h      = (float*)alloc((size_t)NN*D*4);
  unsigned short* t1 = (unsigned short*)alloc((size_t)NE*D*2);  // 204.8 MB
  unsigned short* t2 = (unsigned short*)alloc((size_t)NE*D*2);  // 204.8 MB

  hipMemsetAsync(cursor, 0, (size_t)NN*4, stream);
  k_deg     <<<(NE+255)/256, 256, 0, stream>>>(dstp, cursor);
  k_scan_a  <<<NB_SCAN, 256, 0, stream>>>(cursor, bsum);
  k_scan_b  <<<1, 512, 0, stream>>>(bsum, rowptr);
  k_scan_c  <<<NB_SCAN, 256, 0, stream>>>(bsum, rowptr, cursor);
  k_scatter <<<(NE+255)/256, 256, 0, stream>>>(srcp, dstp, cursor, slot, ssrc);

  // one eattr pass computes both layers' edge transforms
  k_t   <<<4096, 256, 0, stream>>>(eattr, slot, We1, We2, t1, t2);
  k_lin <<<2048, 256, 0, stream>>>(x, W1, b1, xl);
  k_node<<<8192, 256, 0, stream>>>(rowptr, ssrc, t1, att1, xl, bias1, h);
  k_lin <<<2048, 256, 0, stream>>>(h, W2, b2, xl);
  k_node<<<8192, 256, 0, stream>>>(rowptr, ssrc, t2, att2, xl, bias2, out);
}

// Round 10
// 624.518 us; speedup vs baseline: 1.1181x; 1.1181x over previous
//
#include <hip/hip_runtime.h>
#include <math.h>

#define NN 100000
#define NE 1600000
#define D 64
#define DE 32
#define NB_SCAN ((NN + 255) / 256)   // 391

typedef __attribute__((ext_vector_type(8))) short short8;
typedef __attribute__((ext_vector_type(4))) float f32x4;

__device__ __forceinline__ int rfl(int v){ return __builtin_amdgcn_readfirstlane(v); }

#define LEAKY(v) ((v) > 0.f ? (v) : 0.2f*(v))

__device__ __forceinline__ unsigned short f2bf(float x){
  unsigned u = __float_as_uint(x);
  unsigned r = (u + 0x7fffu + ((u >> 16) & 1u)) >> 16;
  return (unsigned short)r;
}
__device__ __forceinline__ float bf2f(unsigned short b){
  return __uint_as_float(((unsigned)b) << 16);
}

// cursor doubles as deg accumulator
__global__ __launch_bounds__(256) void k_deg(const int* __restrict__ dst, int* __restrict__ cursor){
  int i = blockIdx.x*256 + threadIdx.x;
  if (i < NE) atomicAdd(&cursor[dst[i]], 1);
}

__global__ __launch_bounds__(256) void k_scan_a(const int* __restrict__ deg, int* __restrict__ bsum){
  __shared__ int sh[256];
  int tid = threadIdx.x;
  int i = blockIdx.x*256 + tid;
  sh[tid] = (i < NN) ? deg[i] : 0;
  __syncthreads();
  for (int s = 128; s > 0; s >>= 1){
    if (tid < s) sh[tid] += sh[tid+s];
    __syncthreads();
  }
  if (tid == 0) bsum[blockIdx.x] = sh[0];
}

__global__ __launch_bounds__(512) void k_scan_b(int* __restrict__ bsum, int* __restrict__ rowptr){
  __shared__ int tmp[512];
  int tid = threadIdx.x;
  int v = (tid < NB_SCAN) ? bsum[tid] : 0;
  tmp[tid] = v;
  __syncthreads();
  for (int off = 1; off < 512; off <<= 1){
    int t = (tid >= off) ? tmp[tid-off] : 0;
    __syncthreads();
    tmp[tid] += t;
    __syncthreads();
  }
  if (tid < NB_SCAN) bsum[tid] = tmp[tid] - v;
  if (tid == 511) rowptr[NN] = tmp[511];
}

// reads cursor (=deg), writes rowptr and resets cursor to the exclusive offset
__global__ __launch_bounds__(256) void k_scan_c(const int* bsum, int* rowptr, int* cursor){
  __shared__ int tmp[256];
  int tid = threadIdx.x;
  int i = blockIdx.x*256 + tid;
  int v = (i < NN) ? cursor[i] : 0;
  tmp[tid] = v;
  __syncthreads();
  for (int off = 1; off < 256; off <<= 1){
    int t = (tid >= off) ? tmp[tid-off] : 0;
    __syncthreads();
    tmp[tid] += t;
    __syncthreads();
  }
  if (i < NN){
    int excl = tmp[tid] - v + bsum[blockIdx.x];
    rowptr[i] = excl;
    cursor[i] = excl;
  }
}

// slot[pos]=edge id of CSR slot, ssrc[pos]=src node of CSR slot
__global__ __launch_bounds__(256) void k_scatter(const int* __restrict__ srcp, const int* __restrict__ dstp,
                                                 int* __restrict__ cursor,
                                                 int* __restrict__ slot, int* __restrict__ ssrc){
  int i = blockIdx.x*256 + threadIdx.x;
  if (i < NE){
    int d = dstp[i];
    int pos = atomicAdd(&cursor[d], 1);
    slot[pos] = i;
    ssrc[pos] = srcp[i];
  }
}

// t_csr[i][j] = bf16( (eattr[slot[i]] @ We)[j] )  via mfma_f32_16x16x32_bf16.
// One wave per 16 CSR slots (R6-proven body). Random 128B-aligned row reads
// (vector loads), sequential writes. Both layers in one eattr pass.
__global__ __launch_bounds__(256) void k_t(const float* __restrict__ eattr,
                                           const int* __restrict__ slot,
                                           const float* __restrict__ We1,
                                           const float* __restrict__ We2,
                                           unsigned short* __restrict__ t1,
                                           unsigned short* __restrict__ t2){
  int lane = threadIdx.x & 63;
  int wid = blockIdx.x*(blockDim.x>>6) + (threadIdx.x>>6);
  int nw = gridDim.x*(blockDim.x>>6);
  int r = lane & 15;    // A: edge row within tile; B/D: output col within 16-tile
  int g = lane >> 4;    // k-group (A/B), row-group (D)
  // B fragments: wb[t][i] = We[(8g+i)][16t + r]
  short8 wb1[4], wb2[4];
  #pragma unroll
  for (int t = 0; t < 4; ++t){
    #pragma unroll
    for (int i = 0; i < 8; ++i){
      wb1[t][i] = (short)f2bf(We1[(8*g + i)*D + 16*t + r]);
      wb2[t][i] = (short)f2bf(We2[(8*g + i)*D + 16*t + r]);
    }
  }
  for (int i0 = wid*16; i0 < NE; i0 += nw*16){
    int sl = slot[i0 + r];
    const float* ea = eattr + (size_t)sl*DE + 8*g;
    float4 q0 = *(const float4*)(ea);
    float4 q1 = *(const float4*)(ea + 4);
    short8 a;
    a[0]=(short)f2bf(q0.x); a[1]=(short)f2bf(q0.y); a[2]=(short)f2bf(q0.z); a[3]=(short)f2bf(q0.w);
    a[4]=(short)f2bf(q1.x); a[5]=(short)f2bf(q1.y); a[6]=(short)f2bf(q1.z); a[7]=(short)f2bf(q1.w);
    f32x4 d0={0.f,0.f,0.f,0.f}, d1={0.f,0.f,0.f,0.f}, d2={0.f,0.f,0.f,0.f}, d3={0.f,0.f,0.f,0.f};
    d0 = __builtin_amdgcn_mfma_f32_16x16x32_bf16(a, wb1[0], d0, 0, 0, 0);
    d1 = __builtin_amdgcn_mfma_f32_16x16x32_bf16(a, wb1[1], d1, 0, 0, 0);
    d2 = __builtin_amdgcn_mfma_f32_16x16x32_bf16(a, wb1[2], d2, 0, 0, 0);
    d3 = __builtin_amdgcn_mfma_f32_16x16x32_bf16(a, wb1[3], d3, 0, 0, 0);
    size_t rb = (size_t)(i0 + 4*g)*D + r;   // row 4g+i, col 16t+r
    #pragma unroll
    for (int i = 0; i < 4; ++i){
      t1[rb + (size_t)i*D +  0] = f2bf(d0[i]);
      t1[rb + (size_t)i*D + 16] = f2bf(d1[i]);
      t1[rb + (size_t)i*D + 32] = f2bf(d2[i]);
      t1[rb + (size_t)i*D + 48] = f2bf(d3[i]);
    }
    f32x4 e0={0.f,0.f,0.f,0.f}, e1={0.f,0.f,0.f,0.f}, e2={0.f,0.f,0.f,0.f}, e3={0.f,0.f,0.f,0.f};
    e0 = __builtin_amdgcn_mfma_f32_16x16x32_bf16(a, wb2[0], e0, 0, 0, 0);
    e1 = __builtin_amdgcn_mfma_f32_16x16x32_bf16(a, wb2[1], e1, 0, 0, 0);
    e2 = __builtin_amdgcn_mfma_f32_16x16x32_bf16(a, wb2[2], e2, 0, 0, 0);
    e3 = __builtin_amdgcn_mfma_f32_16x16x32_bf16(a, wb2[3], e3, 0, 0, 0);
    #pragma unroll
    for (int i = 0; i < 4; ++i){
      t2[rb + (size_t)i*D +  0] = f2bf(e0[i]);
      t2[rb + (size_t)i*D + 16] = f2bf(e1[i]);
      t2[rb + (size_t)i*D + 32] = f2bf(e2[i]);
      t2[rb + (size_t)i*D + 48] = f2bf(e3[i]);
    }
  }
}

// xl[n][j] = bf16( b[j] + sum_k x[n][k]*W[k][j] )   (bf16 rows: 128B = 1 line)
__global__ __launch_bounds__(256) void k_lin(const float* __restrict__ xin, const float* __restrict__ W,
                                             const float* __restrict__ b, unsigned short* __restrict__ xl){
  int lane = threadIdx.x & 63;
  int wid = blockIdx.x*(blockDim.x>>6) + (threadIdx.x>>6);
  int nw = gridDim.x*(blockDim.x>>6);
  float wcol[D];
  #pragma unroll
  for (int kk = 0; kk < D; ++kk) wcol[kk] = W[kk*D + lane];
  float bj = b[lane];
  for (int n0 = wid; n0 < NN; n0 += nw){
    int n = rfl(n0);
    const float* xr = xin + (size_t)n*D;
    float acc = bj;
    #pragma unroll
    for (int kk = 0; kk < D; ++kk) acc = fmaf(xr[kk], wcol[kk], acc);
    xl[(size_t)n*D + lane] = f2bf(acc);
  }
}

// Fused per-destination: logit + softmax + aggregate.
// Wave = 4 groups x 16 lanes; group g owns edge 4k+g, lane owns dims 4q..4q+3.
// ssrc read coalesced per segment (no scalar-cache chain); 4 edges per
// load instruction; 4-stage within-16 butterfly covers all 64 dims.
__global__ __launch_bounds__(256) void k_node(const int* __restrict__ rowptr,
                                              const int* __restrict__ ssrc,
                                              const unsigned short* __restrict__ t_csr,
                                              const float* __restrict__ att,
                                              const unsigned short* __restrict__ xl,
                                              const float* __restrict__ bias,
                                              float* __restrict__ outp){
  int lane = threadIdx.x & 63;
  int q = lane & 15;          // dim quarter
  int g = lane >> 4;          // edge group
  int wid = blockIdx.x*(blockDim.x>>6) + (threadIdx.x>>6);
  int nw = gridDim.x*(blockDim.x>>6);
  float4 att4 = *(const float4*)(att + 4*q);
  float4 bi4  = *(const float4*)(bias + 4*q);
  for (int n0 = wid; n0 < NN; n0 += nw){
    int n = rfl(n0);
    int st = rowptr[n], en = rowptr[n+1];
    ushort4 xdu = *(const ushort4*)(xl + (size_t)n*D + 4*q);
    float xd0 = bf2f(xdu.x), xd1 = bf2f(xdu.y), xd2 = bf2f(xdu.z), xd3 = bf2f(xdu.w);
    float den = 0.f;
    float ac0=0.f, ac1=0.f, ac2=0.f, ac3=0.f;
    float ts0=0.f, ts1=0.f, ts2=0.f, ts3=0.f;
    for (int c0 = st; c0 < en; c0 += 64){
      int nb = en - c0; if (nb > 64) nb = 64;
      int sv = (c0 + lane < en) ? ssrc[c0 + lane] : 0;   // coalesced
      for (int k = 0; 4*k < nb; ++k){
        int eoff = 4*k + g;
        bool valid = (eoff < nb);
        int row = c0 + (valid ? eoff : 0);
        int si = __shfl(sv, eoff, 64);
        ushort4 tu = *(const ushort4*)(t_csr + (size_t)row*D + 4*q); // 512B/wave seq
        ushort4 xu = *(const ushort4*)(xl + (size_t)si*D + 4*q);     // 4-row gather
        float t0=bf2f(tu.x), t1=bf2f(tu.y), t2=bf2f(tu.z), t3=bf2f(tu.w);
        float x0=bf2f(xu.x), x1=bf2f(xu.y), x2=bf2f(xu.z), x3=bf2f(xu.w);
        float m0 = x0+xd0+t0, m1 = x1+xd1+t1, m2 = x2+xd2+t2, m3 = x3+xd3+t3;
        float part = att4.x*LEAKY(m0);
        part = fmaf(att4.y, LEAKY(m1), part);
        part = fmaf(att4.z, LEAKY(m2), part);
        part = fmaf(att4.w, LEAKY(m3), part);
        part += __shfl_xor(part, 1, 64);
        part += __shfl_xor(part, 2, 64);
        part += __shfl_xor(part, 4, 64);
        part += __shfl_xor(part, 8, 64);
        float c = valid ? part : -1e30f;
        float p = __expf(c);
        den += p;
        if (valid){ ts0 += t0; ts1 += t1; ts2 += t2; ts3 += t3; }
        ac0 = fmaf(p, x0, ac0); ac1 = fmaf(p, x1, ac1);
        ac2 = fmaf(p, x2, ac2); ac3 = fmaf(p, x3, ac3);
      }
    }
    // cross-group combine (different edges per group; same dims per q)
    #pragma unroll
    for (int off = 16; off <= 32; off <<= 1){
      den += __shfl_xor(den, off, 64);
      ac0 += __shfl_xor(ac0, off, 64); ac1 += __shfl_xor(ac1, off, 64);
      ac2 += __shfl_xor(ac2, off, 64); ac3 += __shfl_xor(ac3, off, 64);
      ts0 += __shfl_xor(ts0, off, 64); ts1 += __shfl_xor(ts1, off, 64);
      ts2 += __shfl_xor(ts2, off, 64); ts3 += __shfl_xor(ts3, off, 64);
    }
    // self loop: t_self = mean(t) by linearity; within-16 reduce covers all dims
    float inv = 1.f / fmaxf((float)(en - st), 1.f);
    float s0 = fmaf(ts0, inv, xd0 + xd0);
    float s1 = fmaf(ts1, inv, xd1 + xd1);
    float s2 = fmaf(ts2, inv, xd2 + xd2);
    float s3 = fmaf(ts3, inv, xd3 + xd3);
    float cs = att4.x*LEAKY(s0);
    cs = fmaf(att4.y, LEAKY(s1), cs);
    cs = fmaf(att4.z, LEAKY(s2), cs);
    cs = fmaf(att4.w, LEAKY(s3), cs);
    cs += __shfl_xor(cs, 1, 64);
    cs += __shfl_xor(cs, 2, 64);
    cs += __shfl_xor(cs, 4, 64);
    cs += __shfl_xor(cs, 8, 64);
    float ps = __expf(cs);
    den += ps;
    ac0 = fmaf(ps, xd0, ac0); ac1 = fmaf(ps, xd1, ac1);
    ac2 = fmaf(ps, xd2, ac2); ac3 = fmaf(ps, xd3, ac3);
    if (g == 0){
      float4 o;
      float dinv = 1.f / den;
      o.x = fmaf(ac0, dinv, bi4.x);
      o.y = fmaf(ac1, dinv, bi4.y);
      o.z = fmaf(ac2, dinv, bi4.z);
      o.w = fmaf(ac3, dinv, bi4.w);
      *(float4*)(outp + (size_t)n*D + 4*q) = o;
    }
  }
}

extern "C" void kernel_launch(void* const* d_in, const int* in_sizes, int n_in,
                              void* d_out, int out_size, void* d_ws, size_t ws_size,
                              hipStream_t stream){
  const float* x     = (const float*)d_in[0];
  const int*   ei    = (const int*)d_in[1];
  const float* eattr = (const float*)d_in[2];
  const float* W1    = (const float*)d_in[3];
  const float* b1    = (const float*)d_in[4];
  const float* We1   = (const float*)d_in[5];
  const float* att1  = (const float*)d_in[6];
  const float* bias1 = (const float*)d_in[7];
  const float* W2    = (const float*)d_in[8];
  const float* b2    = (const float*)d_in[9];
  const float* We2   = (const float*)d_in[10];
  const float* att2  = (const float*)d_in[11];
  const float* bias2 = (const float*)d_in[12];
  const int* srcp = ei;
  const int* dstp = ei + NE;
  float* out = (float*)d_out;

  char* p = (char*)d_ws;
  size_t off = 0;
  auto alloc = [&](size_t bytes)->char*{
    char* r = p + off; off = (off + bytes + 255) & ~(size_t)255; return r;
  };
  int* rowptr   = (int*)alloc((size_t)(NN+1)*4);
  int* cursor   = (int*)alloc((size_t)NN*4);       // also deg accumulator
  int* bsum     = (int*)alloc(512*4);
  int* slot     = (int*)alloc((size_t)NE*4);
  int* ssrc     = (int*)alloc((size_t)NE*4);
  unsigned short* xl = (unsigned short*)alloc((size_t)NN*D*2);  // bf16 rows
  float* h      = (float*)alloc((size_t)NN*D*4);
  unsigned short* t1 = (unsigned short*)alloc((size_t)NE*D*2);  // 204.8 MB
  unsigned short* t2 = (unsigned short*)alloc((size_t)NE*D*2);  // 204.8 MB

  hipMemsetAsync(cursor, 0, (size_t)NN*4, stream);
  k_deg     <<<(NE+255)/256, 256, 0, stream>>>(dstp, cursor);
  k_scan_a  <<<NB_SCAN, 256, 0, stream>>>(cursor, bsum);
  k_scan_b  <<<1, 512, 0, stream>>>(bsum, rowptr);
  k_scan_c  <<<NB_SCAN, 256, 0, stream>>>(bsum, rowptr, cursor);
  k_scatter <<<(NE+255)/256, 256, 0, stream>>>(srcp, dstp, cursor, slot, ssrc);

  // one eattr pass computes both layers' edge transforms
  k_t   <<<4096, 256, 0, stream>>>(eattr, slot, We1, We2, t1, t2);
  k_lin <<<2048, 256, 0, stream>>>(x, W1, b1, xl);
  k_node<<<8192, 256, 0, stream>>>(rowptr, ssrc, t1, att1, xl, bias1, h);
  k_lin <<<2048, 256, 0, stream>>>(h, W2, b2, xl);
  k_node<<<8192, 256, 0, stream>>>(rowptr, ssrc, t2, att2, xl, bias2, out);
}

// Round 11
// 569.221 us; speedup vs baseline: 1.2268x; 1.0971x over previous
//
#include <hip/hip_runtime.h>
#include <math.h>

#define NN 100000
#define NE 1600000
#define D 64
#define DE 32
#define NB_SCAN ((NN + 255) / 256)   // 391

typedef __attribute__((ext_vector_type(8))) short short8;
typedef __attribute__((ext_vector_type(4))) float f32x4;

__device__ __forceinline__ int rfl(int v){ return __builtin_amdgcn_readfirstlane(v); }

#define LEAKY(v) ((v) > 0.f ? (v) : 0.2f*(v))

__device__ __forceinline__ unsigned short f2bf(float x){
  unsigned u = __float_as_uint(x);
  unsigned r = (u + 0x7fffu + ((u >> 16) & 1u)) >> 16;
  return (unsigned short)r;
}
__device__ __forceinline__ float bf2f(unsigned short b){
  return __uint_as_float(((unsigned)b) << 16);
}

// cursor doubles as deg accumulator
__global__ __launch_bounds__(256) void k_deg(const int* __restrict__ dst, int* __restrict__ cursor){
  int i = blockIdx.x*256 + threadIdx.x;
  if (i < NE) atomicAdd(&cursor[dst[i]], 1);
}

__global__ __launch_bounds__(256) void k_scan_a(const int* __restrict__ deg, int* __restrict__ bsum){
  __shared__ int sh[256];
  int tid = threadIdx.x;
  int i = blockIdx.x*256 + tid;
  sh[tid] = (i < NN) ? deg[i] : 0;
  __syncthreads();
  for (int s = 128; s > 0; s >>= 1){
    if (tid < s) sh[tid] += sh[tid+s];
    __syncthreads();
  }
  if (tid == 0) bsum[blockIdx.x] = sh[0];
}

__global__ __launch_bounds__(512) void k_scan_b(int* __restrict__ bsum, int* __restrict__ rowptr){
  __shared__ int tmp[512];
  int tid = threadIdx.x;
  int v = (tid < NB_SCAN) ? bsum[tid] : 0;
  tmp[tid] = v;
  __syncthreads();
  for (int off = 1; off < 512; off <<= 1){
    int t = (tid >= off) ? tmp[tid-off] : 0;
    __syncthreads();
    tmp[tid] += t;
    __syncthreads();
  }
  if (tid < NB_SCAN) bsum[tid] = tmp[tid] - v;
  if (tid == 511) rowptr[NN] = tmp[511];
}

// reads cursor (=deg), writes rowptr and resets cursor to the exclusive offset
__global__ __launch_bounds__(256) void k_scan_c(const int* bsum, int* rowptr, int* cursor){
  __shared__ int tmp[256];
  int tid = threadIdx.x;
  int i = blockIdx.x*256 + tid;
  int v = (i < NN) ? cursor[i] : 0;
  tmp[tid] = v;
  __syncthreads();
  for (int off = 1; off < 256; off <<= 1){
    int t = (tid >= off) ? tmp[tid-off] : 0;
    __syncthreads();
    tmp[tid] += t;
    __syncthreads();
  }
  if (i < NN){
    int excl = tmp[tid] - v + bsum[blockIdx.x];
    rowptr[i] = excl;
    cursor[i] = excl;
  }
}

// slot[pos]=edge id of CSR slot, ssrc[pos]=src node of CSR slot
__global__ __launch_bounds__(256) void k_scatter(const int* __restrict__ srcp, const int* __restrict__ dstp,
                                                 int* __restrict__ cursor,
                                                 int* __restrict__ slot, int* __restrict__ ssrc){
  int i = blockIdx.x*256 + threadIdx.x;
  if (i < NE){
    int d = dstp[i];
    int pos = atomicAdd(&cursor[d], 1);
    slot[pos] = i;
    ssrc[pos] = srcp[i];
  }
}

// t_csr[i][j] = bf16( (eattr[slot[i]] @ We)[j] )  via mfma_f32_16x16x32_bf16.
// B-tiles carry PERMUTED We columns (tile j holds cols {4c+j}), so lane r owns
// cols 4r..4r+3 of each output row -> packed ushort4 stores (8 stores/iter vs 32).
// A-side (random 128B row gather) and register budget unchanged vs R6.
__global__ __launch_bounds__(256) void k_t(const float* __restrict__ eattr,
                                           const int* __restrict__ slot,
                                           const float* __restrict__ We1,
                                           const float* __restrict__ We2,
                                           unsigned short* __restrict__ t1,
                                           unsigned short* __restrict__ t2){
  int lane = threadIdx.x & 63;
  int wid = blockIdx.x*(blockDim.x>>6) + (threadIdx.x>>6);
  int nw = gridDim.x*(blockDim.x>>6);
  int r = lane & 15;    // A: edge row within tile; B/D: fragment col
  int g = lane >> 4;    // k-group (A/B), row-group (D)
  // B fragments, column-permuted: wb[j][i] = We[(8g+i)][4*r + j]
  short8 wb1[4], wb2[4];
  #pragma unroll
  for (int j = 0; j < 4; ++j){
    #pragma unroll
    for (int i = 0; i < 8; ++i){
      wb1[j][i] = (short)f2bf(We1[(8*g + i)*D + 4*r + j]);
      wb2[j][i] = (short)f2bf(We2[(8*g + i)*D + 4*r + j]);
    }
  }
  for (int i0 = wid*16; i0 < NE; i0 += nw*16){
    int sl = slot[i0 + r];
    const float* ea = eattr + (size_t)sl*DE + 8*g;
    float4 q0 = *(const float4*)(ea);
    float4 q1 = *(const float4*)(ea + 4);
    short8 a;
    a[0]=(short)f2bf(q0.x); a[1]=(short)f2bf(q0.y); a[2]=(short)f2bf(q0.z); a[3]=(short)f2bf(q0.w);
    a[4]=(short)f2bf(q1.x); a[5]=(short)f2bf(q1.y); a[6]=(short)f2bf(q1.z); a[7]=(short)f2bf(q1.w);
    f32x4 d0={0.f,0.f,0.f,0.f}, d1={0.f,0.f,0.f,0.f}, d2={0.f,0.f,0.f,0.f}, d3={0.f,0.f,0.f,0.f};
    d0 = __builtin_amdgcn_mfma_f32_16x16x32_bf16(a, wb1[0], d0, 0, 0, 0);
    d1 = __builtin_amdgcn_mfma_f32_16x16x32_bf16(a, wb1[1], d1, 0, 0, 0);
    d2 = __builtin_amdgcn_mfma_f32_16x16x32_bf16(a, wb1[2], d2, 0, 0, 0);
    d3 = __builtin_amdgcn_mfma_f32_16x16x32_bf16(a, wb1[3], d3, 0, 0, 0);
    // D_j: lane(r,g) -> rows 4g+i, col 4r+j  => ushort4 {d0[i],d1[i],d2[i],d3[i]}
    size_t rowb = (size_t)(i0 + 4*g)*D + 4*r;
    #pragma unroll
    for (int i = 0; i < 4; ++i){
      ushort4 pk;
      pk.x = f2bf(d0[i]); pk.y = f2bf(d1[i]); pk.z = f2bf(d2[i]); pk.w = f2bf(d3[i]);
      *(ushort4*)(t1 + rowb + (size_t)i*D) = pk;
    }
    f32x4 e0={0.f,0.f,0.f,0.f}, e1={0.f,0.f,0.f,0.f}, e2={0.f,0.f,0.f,0.f}, e3={0.f,0.f,0.f,0.f};
    e0 = __builtin_amdgcn_mfma_f32_16x16x32_bf16(a, wb2[0], e0, 0, 0, 0);
    e1 = __builtin_amdgcn_mfma_f32_16x16x32_bf16(a, wb2[1], e1, 0, 0, 0);
    e2 = __builtin_amdgcn_mfma_f32_16x16x32_bf16(a, wb2[2], e2, 0, 0, 0);
    e3 = __builtin_amdgcn_mfma_f32_16x16x32_bf16(a, wb2[3], e3, 0, 0, 0);
    #pragma unroll
    for (int i = 0; i < 4; ++i){
      ushort4 pk;
      pk.x = f2bf(e0[i]); pk.y = f2bf(e1[i]); pk.z = f2bf(e2[i]); pk.w = f2bf(e3[i]);
      *(ushort4*)(t2 + rowb + (size_t)i*D) = pk;
    }
  }
}

// xl[n][j] = bf16( b[j] + sum_k x[n][k]*W[k][j] )   (bf16 rows: 128B = 1 line)
__global__ __launch_bounds__(256) void k_lin(const float* __restrict__ xin, const float* __restrict__ W,
                                             const float* __restrict__ b, unsigned short* __restrict__ xl){
  int lane = threadIdx.x & 63;
  int wid = blockIdx.x*(blockDim.x>>6) + (threadIdx.x>>6);
  int nw = gridDim.x*(blockDim.x>>6);
  float wcol[D];
  #pragma unroll
  for (int kk = 0; kk < D; ++kk) wcol[kk] = W[kk*D + lane];
  float bj = b[lane];
  for (int n0 = wid; n0 < NN; n0 += nw){
    int n = rfl(n0);
    const float* xr = xin + (size_t)n*D;
    float acc = bj;
    #pragma unroll
    for (int kk = 0; kk < D; ++kk) acc = fmaf(xr[kk], wcol[kk], acc);
    xl[(size_t)n*D + lane] = f2bf(acc);
  }
}

// Fused per-destination: logit + softmax + aggregate.
// Wave = 4 groups x 16 lanes; group g owns one edge per 4; lane owns 4 dims.
// Inner loop unrolled x2: 8 edges per iteration, 4 loads in flight.
__global__ __launch_bounds__(256) void k_node(const int* __restrict__ rowptr,
                                              const int* __restrict__ ssrc,
                                              const unsigned short* __restrict__ t_csr,
                                              const float* __restrict__ att,
                                              const unsigned short* __restrict__ xl,
                                              const float* __restrict__ bias,
                                              float* __restrict__ outp){
  int lane = threadIdx.x & 63;
  int q = lane & 15;          // dim quarter
  int g = lane >> 4;          // edge group
  int wid = blockIdx.x*(blockDim.x>>6) + (threadIdx.x>>6);
  int nw = gridDim.x*(blockDim.x>>6);
  float4 att4 = *(const float4*)(att + 4*q);
  float4 bi4  = *(const float4*)(bias + 4*q);
  for (int n0 = wid; n0 < NN; n0 += nw){
    int n = rfl(n0);
    int st = rowptr[n], en = rowptr[n+1];
    ushort4 xdu = *(const ushort4*)(xl + (size_t)n*D + 4*q);
    float xd0 = bf2f(xdu.x), xd1 = bf2f(xdu.y), xd2 = bf2f(xdu.z), xd3 = bf2f(xdu.w);
    float den = 0.f;
    float ac0=0.f, ac1=0.f, ac2=0.f, ac3=0.f;
    float ts0=0.f, ts1=0.f, ts2=0.f, ts3=0.f;
    for (int c0 = st; c0 < en; c0 += 64){
      int nb = en - c0; if (nb > 64) nb = 64;
      int sv = (c0 + lane < en) ? ssrc[c0 + lane] : 0;   // coalesced
      for (int k4 = 0; k4 < nb; k4 += 8){
        int eA = k4 + g,  eB = k4 + 4 + g;
        bool vA = (eA < nb), vB = (eB < nb);
        int rowA = c0 + (vA ? eA : 0);
        int rowB = c0 + (vB ? eB : 0);
        int siA = __shfl(sv, vA ? eA : 0, 64);
        int siB = __shfl(sv, vB ? eB : 0, 64);
        ushort4 tuA = *(const ushort4*)(t_csr + (size_t)rowA*D + 4*q);
        ushort4 xuA = *(const ushort4*)(xl + (size_t)siA*D + 4*q);
        ushort4 tuB = *(const ushort4*)(t_csr + (size_t)rowB*D + 4*q);
        ushort4 xuB = *(const ushort4*)(xl + (size_t)siB*D + 4*q);
        float tA0=bf2f(tuA.x), tA1=bf2f(tuA.y), tA2=bf2f(tuA.z), tA3=bf2f(tuA.w);
        float xA0=bf2f(xuA.x), xA1=bf2f(xuA.y), xA2=bf2f(xuA.z), xA3=bf2f(xuA.w);
        float tB0=bf2f(tuB.x), tB1=bf2f(tuB.y), tB2=bf2f(tuB.z), tB3=bf2f(tuB.w);
        float xB0=bf2f(xuB.x), xB1=bf2f(xuB.y), xB2=bf2f(xuB.z), xB3=bf2f(xuB.w);
        float pa = att4.x*LEAKY(xA0+xd0+tA0);
        pa = fmaf(att4.y, LEAKY(xA1+xd1+tA1), pa);
        pa = fmaf(att4.z, LEAKY(xA2+xd2+tA2), pa);
        pa = fmaf(att4.w, LEAKY(xA3+xd3+tA3), pa);
        float pb = att4.x*LEAKY(xB0+xd0+tB0);
        pb = fmaf(att4.y, LEAKY(xB1+xd1+tB1), pb);
        pb = fmaf(att4.z, LEAKY(xB2+xd2+tB2), pb);
        pb = fmaf(att4.w, LEAKY(xB3+xd3+tB3), pb);
        #pragma unroll
        for (int off = 1; off <= 8; off <<= 1){
          pa += __shfl_xor(pa, off, 64);
          pb += __shfl_xor(pb, off, 64);
        }
        float cA = vA ? pa : -1e30f;
        float cB = vB ? pb : -1e30f;
        float pA = __expf(cA), pB = __expf(cB);
        den += pA + pB;
        if (vA){ ts0 += tA0; ts1 += tA1; ts2 += tA2; ts3 += tA3; }
        if (vB){ ts0 += tB0; ts1 += tB1; ts2 += tB2; ts3 += tB3; }
        ac0 = fmaf(pA, xA0, ac0); ac1 = fmaf(pA, xA1, ac1);
        ac2 = fmaf(pA, xA2, ac2); ac3 = fmaf(pA, xA3, ac3);
        ac0 = fmaf(pB, xB0, ac0); ac1 = fmaf(pB, xB1, ac1);
        ac2 = fmaf(pB, xB2, ac2); ac3 = fmaf(pB, xB3, ac3);
      }
    }
    // cross-group combine (different edges per group; same dims per q)
    #pragma unroll
    for (int off = 16; off <= 32; off <<= 1){
      den += __shfl_xor(den, off, 64);
      ac0 += __shfl_xor(ac0, off, 64); ac1 += __shfl_xor(ac1, off, 64);
      ac2 += __shfl_xor(ac2, off, 64); ac3 += __shfl_xor(ac3, off, 64);
      ts0 += __shfl_xor(ts0, off, 64); ts1 += __shfl_xor(ts1, off, 64);
      ts2 += __shfl_xor(ts2, off, 64); ts3 += __shfl_xor(ts3, off, 64);
    }
    // self loop: t_self = mean(t) by linearity; within-16 reduce covers all dims
    float inv = 1.f / fmaxf((float)(en - st), 1.f);
    float s0 = fmaf(ts0, inv, xd0 + xd0);
    float s1 = fmaf(ts1, inv, xd1 + xd1);
    float s2 = fmaf(ts2, inv, xd2 + xd2);
    float s3 = fmaf(ts3, inv, xd3 + xd3);
    float cs = att4.x*LEAKY(s0);
    cs = fmaf(att4.y, LEAKY(s1), cs);
    cs = fmaf(att4.z, LEAKY(s2), cs);
    cs = fmaf(att4.w, LEAKY(s3), cs);
    cs += __shfl_xor(cs, 1, 64);
    cs += __shfl_xor(cs, 2, 64);
    cs += __shfl_xor(cs, 4, 64);
    cs += __shfl_xor(cs, 8, 64);
    float ps = __expf(cs);
    den += ps;
    ac0 = fmaf(ps, xd0, ac0); ac1 = fmaf(ps, xd1, ac1);
    ac2 = fmaf(ps, xd2, ac2); ac3 = fmaf(ps, xd3, ac3);
    if (g == 0){
      float4 o;
      float dinv = 1.f / den;
      o.x = fmaf(ac0, dinv, bi4.x);
      o.y = fmaf(ac1, dinv, bi4.y);
      o.z = fmaf(ac2, dinv, bi4.z);
      o.w = fmaf(ac3, dinv, bi4.w);
      *(float4*)(outp + (size_t)n*D + 4*q) = o;
    }
  }
}

extern "C" void kernel_launch(void* const* d_in, const int* in_sizes, int n_in,
                              void* d_out, int out_size, void* d_ws, size_t ws_size,
                              hipStream_t stream){
  const float* x     = (const float*)d_in[0];
  const int*   ei    = (const int*)d_in[1];
  const float* eattr = (const float*)d_in[2];
  const float* W1    = (const float*)d_in[3];
  const float* b1    = (const float*)d_in[4];
  const float* We1   = (const float*)d_in[5];
  const float* att1  = (const float*)d_in[6];
  const float* bias1 = (const float*)d_in[7];
  const float* W2    = (const float*)d_in[8];
  const float* b2    = (const float*)d_in[9];
  const float* We2   = (const float*)d_in[10];
  const float* att2  = (const float*)d_in[11];
  const float* bias2 = (const float*)d_in[12];
  const int* srcp = ei;
  const int* dstp = ei + NE;
  float* out = (float*)d_out;

  char* p = (char*)d_ws;
  size_t off = 0;
  auto alloc = [&](size_t bytes)->char*{
    char* r = p + off; off = (off + bytes + 255) & ~(size_t)255; return r;
  };
  int* rowptr   = (int*)alloc((size_t)(NN+1)*4);
  int* cursor   = (int*)alloc((size_t)NN*4);       // also deg accumulator
  int* bsum     = (int*)alloc(512*4);
  int* slot     = (int*)alloc((size_t)NE*4);
  int* ssrc     = (int*)alloc((size_t)NE*4);
  unsigned short* xl = (unsigned short*)alloc((size_t)NN*D*2);  // bf16 rows
  float* h      = (float*)alloc((size_t)NN*D*4);
  unsigned short* t1 = (unsigned short*)alloc((size_t)NE*D*2);  // 204.8 MB
  unsigned short* t2 = (unsigned short*)alloc((size_t)NE*D*2);  // 204.8 MB

  hipMemsetAsync(cursor, 0, (size_t)NN*4, stream);
  k_deg     <<<(NE+255)/256, 256, 0, stream>>>(dstp, cursor);
  k_scan_a  <<<NB_SCAN, 256, 0, stream>>>(cursor, bsum);
  k_scan_b  <<<1, 512, 0, stream>>>(bsum, rowptr);
  k_scan_c  <<<NB_SCAN, 256, 0, stream>>>(bsum, rowptr, cursor);
  k_scatter <<<(NE+255)/256, 256, 0, stream>>>(srcp, dstp, cursor, slot, ssrc);

  // one eattr pass computes both layers' edge transforms
  k_t   <<<4096, 256, 0, stream>>>(eattr, slot, We1, We2, t1, t2);
  k_lin <<<2048, 256, 0, stream>>>(x, W1, b1, xl);
  k_node<<<8192, 256, 0, stream>>>(rowptr, ssrc, t1, att1, xl, bias1, h);
  k_lin <<<2048, 256, 0, stream>>>(h, W2, b2, xl);
  k_node<<<8192, 256, 0, stream>>>(rowptr, ssrc, t2, att2, xl, bias2, out);
}

// Round 12
// 506.715 us; speedup vs baseline: 1.3781x; 1.1234x over previous
//
#include <hip/hip_runtime.h>
#include <math.h>

#define NN 100000
#define NE 1600000
#define D 64
#define DE 32
#define NB_SCAN ((NN + 255) / 256)   // 391

typedef __attribute__((ext_vector_type(8))) short short8;
typedef __attribute__((ext_vector_type(4))) float f32x4;

__device__ __forceinline__ int rfl(int v){ return __builtin_amdgcn_readfirstlane(v); }

#define LEAKY(v) ((v) > 0.f ? (v) : 0.2f*(v))

__device__ __forceinline__ unsigned short f2bf(float x){
  unsigned u = __float_as_uint(x);
  unsigned r = (u + 0x7fffu + ((u >> 16) & 1u)) >> 16;
  return (unsigned short)r;
}
__device__ __forceinline__ float bf2f(unsigned short b){
  return __uint_as_float(((unsigned)b) << 16);
}

// cursor doubles as deg accumulator
__global__ __launch_bounds__(256) void k_deg(const int* __restrict__ dst, int* __restrict__ cursor){
  int i = blockIdx.x*256 + threadIdx.x;
  if (i < NE) atomicAdd(&cursor[dst[i]], 1);
}

__global__ __launch_bounds__(256) void k_scan_a(const int* __restrict__ deg, int* __restrict__ bsum){
  __shared__ int sh[256];
  int tid = threadIdx.x;
  int i = blockIdx.x*256 + tid;
  sh[tid] = (i < NN) ? deg[i] : 0;
  __syncthreads();
  for (int s = 128; s > 0; s >>= 1){
    if (tid < s) sh[tid] += sh[tid+s];
    __syncthreads();
  }
  if (tid == 0) bsum[blockIdx.x] = sh[0];
}

__global__ __launch_bounds__(512) void k_scan_b(int* __restrict__ bsum, int* __restrict__ rowptr){
  __shared__ int tmp[512];
  int tid = threadIdx.x;
  int v = (tid < NB_SCAN) ? bsum[tid] : 0;
  tmp[tid] = v;
  __syncthreads();
  for (int off = 1; off < 512; off <<= 1){
    int t = (tid >= off) ? tmp[tid-off] : 0;
    __syncthreads();
    tmp[tid] += t;
    __syncthreads();
  }
  if (tid < NB_SCAN) bsum[tid] = tmp[tid] - v;
  if (tid == 511) rowptr[NN] = tmp[511];
}

// reads cursor (=deg), writes rowptr and resets cursor to the exclusive offset
__global__ __launch_bounds__(256) void k_scan_c(const int* bsum, int* rowptr, int* cursor){
  __shared__ int tmp[256];
  int tid = threadIdx.x;
  int i = blockIdx.x*256 + tid;
  int v = (i < NN) ? cursor[i] : 0;
  tmp[tid] = v;
  __syncthreads();
  for (int off = 1; off < 256; off <<= 1){
    int t = (tid >= off) ? tmp[tid-off] : 0;
    __syncthreads();
    tmp[tid] += t;
    __syncthreads();
  }
  if (i < NN){
    int excl = tmp[tid] - v + bsum[blockIdx.x];
    rowptr[i] = excl;
    cursor[i] = excl;
  }
}

// slot[pos]=edge id of CSR slot, ssrc[pos]=src node of CSR slot
__global__ __launch_bounds__(256) void k_scatter(const int* __restrict__ srcp, const int* __restrict__ dstp,
                                                 int* __restrict__ cursor,
                                                 int* __restrict__ slot, int* __restrict__ ssrc){
  int i = blockIdx.x*256 + threadIdx.x;
  if (i < NE){
    int d = dstp[i];
    int pos = atomicAdd(&cursor[d], 1);
    slot[pos] = i;
    ssrc[pos] = srcp[i];
  }
}

// xl[n][j] = bf16( b[j] + sum_k x[n][k]*W[k][j] )   (bf16 rows: 128B = 1 line)
__global__ __launch_bounds__(256) void k_lin(const float* __restrict__ xin, const float* __restrict__ W,
                                             const float* __restrict__ b, unsigned short* __restrict__ xl){
  int lane = threadIdx.x & 63;
  int wid = blockIdx.x*(blockDim.x>>6) + (threadIdx.x>>6);
  int nw = gridDim.x*(blockDim.x>>6);
  float wcol[D];
  #pragma unroll
  for (int kk = 0; kk < D; ++kk) wcol[kk] = W[kk*D + lane];
  float bj = b[lane];
  for (int n0 = wid; n0 < NN; n0 += nw){
    int n = rfl(n0);
    const float* xr = xin + (size_t)n*D;
    float acc = bj;
    #pragma unroll
    for (int kk = 0; kk < D; ++kk) acc = fmaf(xr[kk], wcol[kk], acc);
    xl[(size_t)n*D + lane] = f2bf(acc);
  }
}

// Fully fused per-destination layer: edge MLP (MFMA) + logit + softmax +
// aggregate, no t materialization. Wave per node; edges in tiles of 16.
// Lane (q,g): A-row q (gathers eattr[slot[base+q]], k-slice 8g..8g+7);
// after 4 col-permuted MFMAs, lane holds t[edge 4g+i][dims 4q..4q+3] = d_j[i].
__global__ __launch_bounds__(256) void k_node(const int* __restrict__ rowptr,
                                              const int* __restrict__ slot,
                                              const int* __restrict__ ssrc,
                                              const float* __restrict__ eattr,
                                              const float* __restrict__ We,
                                              const float* __restrict__ att,
                                              const unsigned short* __restrict__ xl,
                                              const float* __restrict__ bias,
                                              float* __restrict__ outp){
  int lane = threadIdx.x & 63;
  int q = lane & 15;          // A-row in tile / D col-group (dims 4q..4q+3)
  int g = lane >> 4;          // A/B k-group / D row-group (edges 4g..4g+3)
  int wid = blockIdx.x*(blockDim.x>>6) + (threadIdx.x>>6);
  int nw = gridDim.x*(blockDim.x>>6);
  // B fragments, column-permuted (R11-verified): wb[j][i] = We[(8g+i)][4q+j]
  short8 wb[4];
  #pragma unroll
  for (int j = 0; j < 4; ++j){
    #pragma unroll
    for (int i = 0; i < 8; ++i){
      wb[j][i] = (short)f2bf(We[(8*g + i)*D + 4*q + j]);
    }
  }
  float4 att4 = *(const float4*)(att + 4*q);
  float4 bi4  = *(const float4*)(bias + 4*q);
  for (int n0 = wid; n0 < NN; n0 += nw){
    int n = rfl(n0);
    int st = rowptr[n], en = rowptr[n+1];
    ushort4 xdu = *(const ushort4*)(xl + (size_t)n*D + 4*q);
    float xd0 = bf2f(xdu.x), xd1 = bf2f(xdu.y), xd2 = bf2f(xdu.z), xd3 = bf2f(xdu.w);
    float den = 0.f;
    float ac0=0.f, ac1=0.f, ac2=0.f, ac3=0.f;
    float ts0=0.f, ts1=0.f, ts2=0.f, ts3=0.f;
    for (int base = st; base < en; base += 16){
      int nb = en - base; if (nb > 16) nb = 16;
      // A fragment: row q of the tile (clamped), k-slice 8g..8g+7
      int rrow = base + ((q < nb) ? q : (nb - 1));
      int sl = slot[rrow];
      const float* ea = eattr + (size_t)sl*DE + 8*g;
      float4 e0 = *(const float4*)(ea);
      float4 e1 = *(const float4*)(ea + 4);
      short8 a;
      a[0]=(short)f2bf(e0.x); a[1]=(short)f2bf(e0.y); a[2]=(short)f2bf(e0.z); a[3]=(short)f2bf(e0.w);
      a[4]=(short)f2bf(e1.x); a[5]=(short)f2bf(e1.y); a[6]=(short)f2bf(e1.z); a[7]=(short)f2bf(e1.w);
      f32x4 d0={0.f,0.f,0.f,0.f}, d1={0.f,0.f,0.f,0.f}, d2={0.f,0.f,0.f,0.f}, d3={0.f,0.f,0.f,0.f};
      d0 = __builtin_amdgcn_mfma_f32_16x16x32_bf16(a, wb[0], d0, 0, 0, 0);
      d1 = __builtin_amdgcn_mfma_f32_16x16x32_bf16(a, wb[1], d1, 0, 0, 0);
      d2 = __builtin_amdgcn_mfma_f32_16x16x32_bf16(a, wb[2], d2, 0, 0, 0);
      d3 = __builtin_amdgcn_mfma_f32_16x16x32_bf16(a, wb[3], d3, 0, 0, 0);
      #pragma unroll
      for (int i = 0; i < 4; ++i){
        int eoff = 4*g + i;
        bool valid = (eoff < nb);
        int eidx = base + (valid ? eoff : 0);
        int si = ssrc[eidx];                                   // 16-lane broadcast
        ushort4 xu = *(const ushort4*)(xl + (size_t)si*D + 4*q);
        float x0=bf2f(xu.x), x1=bf2f(xu.y), x2=bf2f(xu.z), x3=bf2f(xu.w);
        float t0 = d0[i], t1 = d1[i], t2 = d2[i], t3 = d3[i];
        float part = att4.x*LEAKY(x0+xd0+t0);
        part = fmaf(att4.y, LEAKY(x1+xd1+t1), part);
        part = fmaf(att4.z, LEAKY(x2+xd2+t2), part);
        part = fmaf(att4.w, LEAKY(x3+xd3+t3), part);
        part += __shfl_xor(part, 1, 64);
        part += __shfl_xor(part, 2, 64);
        part += __shfl_xor(part, 4, 64);
        part += __shfl_xor(part, 8, 64);
        float c = valid ? part : -1e30f;
        float p = __expf(c);
        den += p;
        if (valid){ ts0 += t0; ts1 += t1; ts2 += t2; ts3 += t3; }
        ac0 = fmaf(p, x0, ac0); ac1 = fmaf(p, x1, ac1);
        ac2 = fmaf(p, x2, ac2); ac3 = fmaf(p, x3, ac3);
      }
    }
    // cross-group combine (different edges per group; same dims per q)
    #pragma unroll
    for (int off = 16; off <= 32; off <<= 1){
      den += __shfl_xor(den, off, 64);
      ac0 += __shfl_xor(ac0, off, 64); ac1 += __shfl_xor(ac1, off, 64);
      ac2 += __shfl_xor(ac2, off, 64); ac3 += __shfl_xor(ac3, off, 64);
      ts0 += __shfl_xor(ts0, off, 64); ts1 += __shfl_xor(ts1, off, 64);
      ts2 += __shfl_xor(ts2, off, 64); ts3 += __shfl_xor(ts3, off, 64);
    }
    // self loop: t_self = mean(t) by linearity; 0 for isolated nodes
    float inv = 1.f / fmaxf((float)(en - st), 1.f);
    float s0 = fmaf(ts0, inv, xd0 + xd0);
    float s1 = fmaf(ts1, inv, xd1 + xd1);
    float s2 = fmaf(ts2, inv, xd2 + xd2);
    float s3 = fmaf(ts3, inv, xd3 + xd3);
    float cs = att4.x*LEAKY(s0);
    cs = fmaf(att4.y, LEAKY(s1), cs);
    cs = fmaf(att4.z, LEAKY(s2), cs);
    cs = fmaf(att4.w, LEAKY(s3), cs);
    cs += __shfl_xor(cs, 1, 64);
    cs += __shfl_xor(cs, 2, 64);
    cs += __shfl_xor(cs, 4, 64);
    cs += __shfl_xor(cs, 8, 64);
    float ps = __expf(cs);
    den += ps;
    ac0 = fmaf(ps, xd0, ac0); ac1 = fmaf(ps, xd1, ac1);
    ac2 = fmaf(ps, xd2, ac2); ac3 = fmaf(ps, xd3, ac3);
    if (g == 0){
      float4 o;
      float dinv = 1.f / den;
      o.x = fmaf(ac0, dinv, bi4.x);
      o.y = fmaf(ac1, dinv, bi4.y);
      o.z = fmaf(ac2, dinv, bi4.z);
      o.w = fmaf(ac3, dinv, bi4.w);
      *(float4*)(outp + (size_t)n*D + 4*q) = o;
    }
  }
}

extern "C" void kernel_launch(void* const* d_in, const int* in_sizes, int n_in,
                              void* d_out, int out_size, void* d_ws, size_t ws_size,
                              hipStream_t stream){
  const float* x     = (const float*)d_in[0];
  const int*   ei    = (const int*)d_in[1];
  const float* eattr = (const float*)d_in[2];
  const float* W1    = (const float*)d_in[3];
  const float* b1    = (const float*)d_in[4];
  const float* We1   = (const float*)d_in[5];
  const float* att1  = (const float*)d_in[6];
  const float* bias1 = (const float*)d_in[7];
  const float* W2    = (const float*)d_in[8];
  const float* b2    = (const float*)d_in[9];
  const float* We2   = (const float*)d_in[10];
  const float* att2  = (const float*)d_in[11];
  const float* bias2 = (const float*)d_in[12];
  const int* srcp = ei;
  const int* dstp = ei + NE;
  float* out = (float*)d_out;

  char* p = (char*)d_ws;
  size_t off = 0;
  auto alloc = [&](size_t bytes)->char*{
    char* r = p + off; off = (off + bytes + 255) & ~(size_t)255; return r;
  };
  int* rowptr   = (int*)alloc((size_t)(NN+1)*4);
  int* cursor   = (int*)alloc((size_t)NN*4);       // also deg accumulator
  int* bsum     = (int*)alloc(512*4);
  int* slot     = (int*)alloc((size_t)NE*4);
  int* ssrc     = (int*)alloc((size_t)NE*4);
  unsigned short* xl = (unsigned short*)alloc((size_t)NN*D*2);  // bf16 rows
  float* h      = (float*)alloc((size_t)NN*D*4);

  hipMemsetAsync(cursor, 0, (size_t)NN*4, stream);
  k_deg     <<<(NE+255)/256, 256, 0, stream>>>(dstp, cursor);
  k_scan_a  <<<NB_SCAN, 256, 0, stream>>>(cursor, bsum);
  k_scan_b  <<<1, 512, 0, stream>>>(bsum, rowptr);
  k_scan_c  <<<NB_SCAN, 256, 0, stream>>>(bsum, rowptr, cursor);
  k_scatter <<<(NE+255)/256, 256, 0, stream>>>(srcp, dstp, cursor, slot, ssrc);

  // layer 1
  k_lin <<<2048, 256, 0, stream>>>(x, W1, b1, xl);
  k_node<<<8192, 256, 0, stream>>>(rowptr, slot, ssrc, eattr, We1, att1, xl, bias1, h);
  // layer 2
  k_lin <<<2048, 256, 0, stream>>>(h, W2, b2, xl);
  k_node<<<8192, 256, 0, stream>>>(rowptr, slot, ssrc, eattr, We2, att2, xl, bias2, out);
}

// Round 13
// 442.048 us; speedup vs baseline: 1.5797x; 1.1463x over previous
//
#include <hip/hip_runtime.h>
#include <math.h>

#define NN 100000
#define NE 1600000
#define D 64
#define DE 32
#define NB_SCAN ((NN + 255) / 256)   // 391

typedef __attribute__((ext_vector_type(8))) short short8;
typedef __attribute__((ext_vector_type(4))) float f32x4;

__device__ __forceinline__ int rfl(int v){ return __builtin_amdgcn_readfirstlane(v); }

#define LEAKY(v) fmaxf((v), 0.2f*(v))

__device__ __forceinline__ unsigned short f2bf(float x){
  unsigned u = __float_as_uint(x);
  unsigned r = (u + 0x7fffu + ((u >> 16) & 1u)) >> 16;
  return (unsigned short)r;
}
__device__ __forceinline__ float bf2f(unsigned short b){
  return __uint_as_float(((unsigned)b) << 16);
}

// cursor doubles as deg accumulator
__global__ __launch_bounds__(256) void k_deg(const int* __restrict__ dst, int* __restrict__ cursor){
  int i = blockIdx.x*256 + threadIdx.x;
  if (i < NE) atomicAdd(&cursor[dst[i]], 1);
}

__global__ __launch_bounds__(256) void k_scan_a(const int* __restrict__ deg, int* __restrict__ bsum){
  __shared__ int sh[256];
  int tid = threadIdx.x;
  int i = blockIdx.x*256 + tid;
  sh[tid] = (i < NN) ? deg[i] : 0;
  __syncthreads();
  for (int s = 128; s > 0; s >>= 1){
    if (tid < s) sh[tid] += sh[tid+s];
    __syncthreads();
  }
  if (tid == 0) bsum[blockIdx.x] = sh[0];
}

__global__ __launch_bounds__(512) void k_scan_b(int* __restrict__ bsum, int* __restrict__ rowptr){
  __shared__ int tmp[512];
  int tid = threadIdx.x;
  int v = (tid < NB_SCAN) ? bsum[tid] : 0;
  tmp[tid] = v;
  __syncthreads();
  for (int off = 1; off < 512; off <<= 1){
    int t = (tid >= off) ? tmp[tid-off] : 0;
    __syncthreads();
    tmp[tid] += t;
    __syncthreads();
  }
  if (tid < NB_SCAN) bsum[tid] = tmp[tid] - v;
  if (tid == 511) rowptr[NN] = tmp[511];
}

// reads cursor (=deg), writes rowptr and resets cursor to the exclusive offset
__global__ __launch_bounds__(256) void k_scan_c(const int* bsum, int* rowptr, int* cursor){
  __shared__ int tmp[256];
  int tid = threadIdx.x;
  int i = blockIdx.x*256 + tid;
  int v = (i < NN) ? cursor[i] : 0;
  tmp[tid] = v;
  __syncthreads();
  for (int off = 1; off < 256; off <<= 1){
    int t = (tid >= off) ? tmp[tid-off] : 0;
    __syncthreads();
    tmp[tid] += t;
    __syncthreads();
  }
  if (i < NN){
    int excl = tmp[tid] - v + bsum[blockIdx.x];
    rowptr[i] = excl;
    cursor[i] = excl;
  }
}

// slot[pos]=edge id of CSR slot, ssrc[pos]=src node of CSR slot
__global__ __launch_bounds__(256) void k_scatter(const int* __restrict__ srcp, const int* __restrict__ dstp,
                                                 int* __restrict__ cursor,
                                                 int* __restrict__ slot, int* __restrict__ ssrc){
  int i = blockIdx.x*256 + threadIdx.x;
  if (i < NE){
    int d = dstp[i];
    int pos = atomicAdd(&cursor[d], 1);
    slot[pos] = i;
    ssrc[pos] = srcp[i];
  }
}

// MFMA linear: xl[n][j] = bf16( b[j] + sum_k x[n][k]*W[k][j] ).
// Wave per 16-node tile (NN%16==0). A = 16 x-rows (coalesced float4 loads);
// B = W col-permuted (R11 recipe), K=64 = 2 chained MFMAs, C init = bias.
__global__ __launch_bounds__(256) void k_lin(const float* __restrict__ xin, const float* __restrict__ W,
                                             const float* __restrict__ b, unsigned short* __restrict__ xl){
  int lane = threadIdx.x & 63;
  int q = lane & 15, g = lane >> 4;
  int wid = blockIdx.x*(blockDim.x>>6) + (threadIdx.x>>6);
  int nw = gridDim.x*(blockDim.x>>6);
  // B frags, col-permuted: wb[kk][j][i] = W[(32kk + 8g+i)][4q+j]
  short8 wb[2][4];
  #pragma unroll
  for (int kk = 0; kk < 2; ++kk)
    #pragma unroll
    for (int j = 0; j < 4; ++j)
      #pragma unroll
      for (int i = 0; i < 8; ++i)
        wb[kk][j][i] = (short)f2bf(W[(32*kk + 8*g + i)*D + 4*q + j]);
  float4 b4 = *(const float4*)(b + 4*q);
  for (int t0 = wid; t0 < NN/16; t0 += nw){
    int n0 = rfl(t0)*16;
    const float* xr = xin + (size_t)(n0 + q)*D + 8*g;
    float4 a0 = *(const float4*)(xr);
    float4 a1 = *(const float4*)(xr + 4);
    float4 a2 = *(const float4*)(xr + 32);
    float4 a3 = *(const float4*)(xr + 36);
    short8 af0, af1;
    af0[0]=(short)f2bf(a0.x); af0[1]=(short)f2bf(a0.y); af0[2]=(short)f2bf(a0.z); af0[3]=(short)f2bf(a0.w);
    af0[4]=(short)f2bf(a1.x); af0[5]=(short)f2bf(a1.y); af0[6]=(short)f2bf(a1.z); af0[7]=(short)f2bf(a1.w);
    af1[0]=(short)f2bf(a2.x); af1[1]=(short)f2bf(a2.y); af1[2]=(short)f2bf(a2.z); af1[3]=(short)f2bf(a2.w);
    af1[4]=(short)f2bf(a3.x); af1[5]=(short)f2bf(a3.y); af1[6]=(short)f2bf(a3.z); af1[7]=(short)f2bf(a3.w);
    f32x4 acc0 = {b4.x, b4.x, b4.x, b4.x};
    f32x4 acc1 = {b4.y, b4.y, b4.y, b4.y};
    f32x4 acc2 = {b4.z, b4.z, b4.z, b4.z};
    f32x4 acc3 = {b4.w, b4.w, b4.w, b4.w};
    acc0 = __builtin_amdgcn_mfma_f32_16x16x32_bf16(af0, wb[0][0], acc0, 0, 0, 0);
    acc1 = __builtin_amdgcn_mfma_f32_16x16x32_bf16(af0, wb[0][1], acc1, 0, 0, 0);
    acc2 = __builtin_amdgcn_mfma_f32_16x16x32_bf16(af0, wb[0][2], acc2, 0, 0, 0);
    acc3 = __builtin_amdgcn_mfma_f32_16x16x32_bf16(af0, wb[0][3], acc3, 0, 0, 0);
    acc0 = __builtin_amdgcn_mfma_f32_16x16x32_bf16(af1, wb[1][0], acc0, 0, 0, 0);
    acc1 = __builtin_amdgcn_mfma_f32_16x16x32_bf16(af1, wb[1][1], acc1, 0, 0, 0);
    acc2 = __builtin_amdgcn_mfma_f32_16x16x32_bf16(af1, wb[1][2], acc2, 0, 0, 0);
    acc3 = __builtin_amdgcn_mfma_f32_16x16x32_bf16(af1, wb[1][3], acc3, 0, 0, 0);
    // D: row 4g+i, cols 4q..4q+3
    #pragma unroll
    for (int i = 0; i < 4; ++i){
      ushort4 pk;
      pk.x = f2bf(acc0[i]); pk.y = f2bf(acc1[i]); pk.z = f2bf(acc2[i]); pk.w = f2bf(acc3[i]);
      *(ushort4*)(xl + (size_t)(n0 + 4*g + i)*D + 4*q) = pk;
    }
  }
}

// Fully fused per-destination layer: edge MLP (MFMA) + logit + softmax +
// aggregate, no t materialization. Wave per node; edges in tiles of 16.
__global__ __launch_bounds__(256) void k_node(const int* __restrict__ rowptr,
                                              const int* __restrict__ slot,
                                              const int* __restrict__ ssrc,
                                              const float* __restrict__ eattr,
                                              const float* __restrict__ We,
                                              const float* __restrict__ att,
                                              const unsigned short* __restrict__ xl,
                                              const float* __restrict__ bias,
                                              float* __restrict__ outp){
  int lane = threadIdx.x & 63;
  int q = lane & 15;          // A-row in tile / D col-group (dims 4q..4q+3)
  int g = lane >> 4;          // A/B k-group / D row-group (edges 4g..4g+3)
  int wid = blockIdx.x*(blockDim.x>>6) + (threadIdx.x>>6);
  int nw = gridDim.x*(blockDim.x>>6);
  // B fragments, column-permuted (R11-verified): wb[j][i] = We[(8g+i)][4q+j]
  short8 wb[4];
  #pragma unroll
  for (int j = 0; j < 4; ++j){
    #pragma unroll
    for (int i = 0; i < 8; ++i){
      wb[j][i] = (short)f2bf(We[(8*g + i)*D + 4*q + j]);
    }
  }
  float4 att4 = *(const float4*)(att + 4*q);
  float4 bi4  = *(const float4*)(bias + 4*q);
  for (int n0 = wid; n0 < NN; n0 += nw){
    int n = rfl(n0);
    int st = rowptr[n], en = rowptr[n+1];
    ushort4 xdu = *(const ushort4*)(xl + (size_t)n*D + 4*q);
    float xd0 = bf2f(xdu.x), xd1 = bf2f(xdu.y), xd2 = bf2f(xdu.z), xd3 = bf2f(xdu.w);
    float den = 0.f;
    float ac0=0.f, ac1=0.f, ac2=0.f, ac3=0.f;
    float ts0=0.f, ts1=0.f, ts2=0.f, ts3=0.f;
    for (int base = st; base < en; base += 16){
      int nb = en - base; if (nb > 16) nb = 16;
      // A fragment: row q of the tile (clamped), k-slice 8g..8g+7
      int rrow = base + ((q < nb) ? q : (nb - 1));
      int sl = slot[rrow];
      const float* ea = eattr + (size_t)sl*DE + 8*g;
      float4 e0 = *(const float4*)(ea);
      float4 e1 = *(const float4*)(ea + 4);
      short8 a;
      a[0]=(short)f2bf(e0.x); a[1]=(short)f2bf(e0.y); a[2]=(short)f2bf(e0.z); a[3]=(short)f2bf(e0.w);
      a[4]=(short)f2bf(e1.x); a[5]=(short)f2bf(e1.y); a[6]=(short)f2bf(e1.z); a[7]=(short)f2bf(e1.w);
      f32x4 d0={0.f,0.f,0.f,0.f}, d1={0.f,0.f,0.f,0.f}, d2={0.f,0.f,0.f,0.f}, d3={0.f,0.f,0.f,0.f};
      d0 = __builtin_amdgcn_mfma_f32_16x16x32_bf16(a, wb[0], d0, 0, 0, 0);
      d1 = __builtin_amdgcn_mfma_f32_16x16x32_bf16(a, wb[1], d1, 0, 0, 0);
      d2 = __builtin_amdgcn_mfma_f32_16x16x32_bf16(a, wb[2], d2, 0, 0, 0);
      d3 = __builtin_amdgcn_mfma_f32_16x16x32_bf16(a, wb[3], d3, 0, 0, 0);
      #pragma unroll
      for (int i = 0; i < 4; ++i){
        int eoff = 4*g + i;
        bool valid = (eoff < nb);
        int eidx = base + (valid ? eoff : 0);
        int si = ssrc[eidx];                                   // 16-lane broadcast
        ushort4 xu = *(const ushort4*)(xl + (size_t)si*D + 4*q);
        float x0=bf2f(xu.x), x1=bf2f(xu.y), x2=bf2f(xu.z), x3=bf2f(xu.w);
        float t0 = d0[i], t1 = d1[i], t2 = d2[i], t3 = d3[i];
        float part = att4.x*LEAKY(x0+xd0+t0);
        part = fmaf(att4.y, LEAKY(x1+xd1+t1), part);
        part = fmaf(att4.z, LEAKY(x2+xd2+t2), part);
        part = fmaf(att4.w, LEAKY(x3+xd3+t3), part);
        part += __shfl_xor(part, 1, 64);
        part += __shfl_xor(part, 2, 64);
        part += __shfl_xor(part, 4, 64);
        part += __shfl_xor(part, 8, 64);
        float c = valid ? part : -1e30f;
        float p = __expf(c);
        den += p;
        if (valid){ ts0 += t0; ts1 += t1; ts2 += t2; ts3 += t3; }
        ac0 = fmaf(p, x0, ac0); ac1 = fmaf(p, x1, ac1);
        ac2 = fmaf(p, x2, ac2); ac3 = fmaf(p, x3, ac3);
      }
    }
    // cross-group combine (different edges per group; same dims per q)
    #pragma unroll
    for (int off = 16; off <= 32; off <<= 1){
      den += __shfl_xor(den, off, 64);
      ac0 += __shfl_xor(ac0, off, 64); ac1 += __shfl_xor(ac1, off, 64);
      ac2 += __shfl_xor(ac2, off, 64); ac3 += __shfl_xor(ac3, off, 64);
      ts0 += __shfl_xor(ts0, off, 64); ts1 += __shfl_xor(ts1, off, 64);
      ts2 += __shfl_xor(ts2, off, 64); ts3 += __shfl_xor(ts3, off, 64);
    }
    // self loop: t_self = mean(t) by linearity; 0 for isolated nodes
    float inv = 1.f / fmaxf((float)(en - st), 1.f);
    float s0 = fmaf(ts0, inv, xd0 + xd0);
    float s1 = fmaf(ts1, inv, xd1 + xd1);
    float s2 = fmaf(ts2, inv, xd2 + xd2);
    float s3 = fmaf(ts3, inv, xd3 + xd3);
    float cs = att4.x*LEAKY(s0);
    cs = fmaf(att4.y, LEAKY(s1), cs);
    cs = fmaf(att4.z, LEAKY(s2), cs);
    cs = fmaf(att4.w, LEAKY(s3), cs);
    cs += __shfl_xor(cs, 1, 64);
    cs += __shfl_xor(cs, 2, 64);
    cs += __shfl_xor(cs, 4, 64);
    cs += __shfl_xor(cs, 8, 64);
    float ps = __expf(cs);
    den += ps;
    ac0 = fmaf(ps, xd0, ac0); ac1 = fmaf(ps, xd1, ac1);
    ac2 = fmaf(ps, xd2, ac2); ac3 = fmaf(ps, xd3, ac3);
    if (g == 0){
      float4 o;
      float dinv = 1.f / den;
      o.x = fmaf(ac0, dinv, bi4.x);
      o.y = fmaf(ac1, dinv, bi4.y);
      o.z = fmaf(ac2, dinv, bi4.z);
      o.w = fmaf(ac3, dinv, bi4.w);
      *(float4*)(outp + (size_t)n*D + 4*q) = o;
    }
  }
}

extern "C" void kernel_launch(void* const* d_in, const int* in_sizes, int n_in,
                              void* d_out, int out_size, void* d_ws, size_t ws_size,
                              hipStream_t stream){
  const float* x     = (const float*)d_in[0];
  const int*   ei    = (const int*)d_in[1];
  const float* eattr = (const float*)d_in[2];
  const float* W1    = (const float*)d_in[3];
  const float* b1    = (const float*)d_in[4];
  const float* We1   = (const float*)d_in[5];
  const float* att1  = (const float*)d_in[6];
  const float* bias1 = (const float*)d_in[7];
  const float* W2    = (const float*)d_in[8];
  const float* b2    = (const float*)d_in[9];
  const float* We2   = (const float*)d_in[10];
  const float* att2  = (const float*)d_in[11];
  const float* bias2 = (const float*)d_in[12];
  const int* srcp = ei;
  const int* dstp = ei + NE;
  float* out = (float*)d_out;

  char* p = (char*)d_ws;
  size_t off = 0;
  auto alloc = [&](size_t bytes)->char*{
    char* r = p + off; off = (off + bytes + 255) & ~(size_t)255; return r;
  };
  int* rowptr   = (int*)alloc((size_t)(NN+1)*4);
  int* cursor   = (int*)alloc((size_t)NN*4);       // also deg accumulator
  int* bsum     = (int*)alloc(512*4);
  int* slot     = (int*)alloc((size_t)NE*4);
  int* ssrc     = (int*)alloc((size_t)NE*4);
  unsigned short* xl = (unsigned short*)alloc((size_t)NN*D*2);  // bf16 rows
  float* h      = (float*)alloc((size_t)NN*D*4);

  hipMemsetAsync(cursor, 0, (size_t)NN*4, stream);
  k_deg     <<<(NE+255)/256, 256, 0, stream>>>(dstp, cursor);
  k_scan_a  <<<NB_SCAN, 256, 0, stream>>>(cursor, bsum);
  k_scan_b  <<<1, 512, 0, stream>>>(bsum, rowptr);
  k_scan_c  <<<NB_SCAN, 256, 0, stream>>>(bsum, rowptr, cursor);
  k_scatter <<<(NE+255)/256, 256, 0, stream>>>(srcp, dstp, cursor, slot, ssrc);

  // layer 1
  k_lin <<<1600, 256, 0, stream>>>(x, W1, b1, xl);
  k_node<<<8192, 256, 0, stream>>>(rowptr, slot, ssrc, eattr, We1, att1, xl, bias1, h);
  // layer 2
  k_lin <<<1600, 256, 0, stream>>>(h, W2, b2, xl);
  k_node<<<8192, 256, 0, stream>>>(rowptr, slot, ssrc, eattr, We2, att2, xl, bias2, out);
}